// Round 7
// baseline (1624.090 us; speedup 1.0000x reference)
//
#include <hip/hip_runtime.h>
#include <hip/hip_bf16.h>

// Problem constants
#define BATCH   4
#define NPER    100000
#define NPTS    (BATCH * NPER)     // 400000
#define GRD     32
#define G3      32768
#define LAT     32
#define HID     64
#define NBINS   (BATCH * G3)       // 131072

#define INV2PI 0.15915494309189535f
#define S0SCALE (30.0f * INV2PI)

// Workspace layout (float offsets)
//  [0,8192)       siren A-frags (ushort idx [0,16384))
//  [8192,22528)   modulator A-frags (ushort idx [16384,45056))
//  [32768,...)    mods table [131072][3][64] fp32
#define WS_TABLE 32768
#define TABLE_FLOATS ((size_t)NBINS * 192)
#define WS_COUNTS (WS_TABLE + TABLE_FLOATS)
#define WS_XS4    (WS_COUNTS + NBINS)
#define WS_TOTAL  (WS_XS4 + (size_t)NPTS * 4)
#define WS_NEEDED_BYTES ((size_t)WS_TOTAL * 4)       // ~107.7 MB

// modulator A-frag ushort offsets
#define MF_L0H 16384
#define MF_L0L 18432
#define MF_L1H 20480
#define MF_L1L 26624
#define MF_L2H 32768
#define MF_L2L 38912

typedef short bf16x8 __attribute__((ext_vector_type(8)));
typedef float f32x16 __attribute__((ext_vector_type(16)));

#define C4(v, j) ((j) == 0 ? (v).x : (j) == 1 ? (v).y : (j) == 2 ? (v).z : (v).w)
#define MFMA32(a, b, c) __builtin_amdgcn_mfma_f32_32x32x16_bf16((a), (b), (c), 0, 0, 0)

__device__ __forceinline__ void split_bf16(float v, short& hi, short& lo) {
    __hip_bfloat16 hb = __float2bfloat16(v);
    float hf = __bfloat162float(hb);
    __hip_bfloat16 lb2 = __float2bfloat16(v - hf);
    hi = *(short*)&hb;
    lo = *(short*)&lb2;
}

// cheap truncation split (error compensated by the 3-pass MFMA)
__device__ __forceinline__ void split_trunc(float v, short& hi, short& lo) {
    unsigned u = __float_as_uint(v);
    unsigned hu = u & 0xffff0000u;
    float lof = v - __uint_as_float(hu);
    hi = (short)(hu >> 16);
    lo = (short)(__float_as_uint(lof) >> 16);
}

// sin(2*pi*t), any t
__device__ __forceinline__ float sinrev(float t) {
    return __builtin_amdgcn_sinf(__builtin_amdgcn_fractf(t));
}

__device__ __forceinline__ int point_batch(int P) {
    return (P >= NPER) + (P >= 2 * NPER) + (P >= 3 * NPER);
}

__device__ __forceinline__ int point_key(const float* __restrict__ x, int P) {
    float xg0 = x[P * 3 + 0] * (float)GRD;
    float xg1 = x[P * 3 + 1] * (float)GRD;
    float xg2 = x[P * 3 + 2] * (float)GRD;
    int l0 = min(max((int)(xg0 - 0.5f), 0), GRD - 1);
    int l1 = min(max((int)(xg1 - 0.5f), 0), GRD - 1);
    int l2 = min(max((int)(xg2 - 0.5f), 0), GRD - 1);
    return (point_batch(P) << 15) | ((l0 * GRD + l1) * GRD + l2);
}

// ---------------------------------------------------------------------------
// Kernel 0: pack all MFMA A-fragment tables + zero the sort histogram.
//  - siren w1/w2 (scaled by 1/2pi), split bf16 hi/lo
//  - modulator mw0/mw1/mw2 (unscaled), split bf16 hi/lo
// ---------------------------------------------------------------------------
__global__ void prep_pack(const float* __restrict__ sw1,
                          const float* __restrict__ sw2,
                          const float* __restrict__ mw0,
                          const float* __restrict__ mw1,
                          const float* __restrict__ mw2,
                          float* __restrict__ ws,
                          int* __restrict__ counts) {
    int tid = threadIdx.x + blockIdx.x * blockDim.x;
    int stride = blockDim.x * gridDim.x;
    unsigned short* fr = (unsigned short*)ws;

    // siren layer-1/2 fragments
    for (int e = tid; e < 8192; e += stride) {
        int layer = e >> 12;
        int r = e & 4095;
        int el = r & 7;
        int lane = (r >> 3) & 63;
        int nt = (r >> 9) & 1;
        int t = r >> 10;
        int k = t * 16 + (lane >> 5) * 8 + el;
        int n = nt * 32 + (lane & 31);
        const float* w = layer ? sw2 : sw1;
        float v = w[k * 64 + n] * INV2PI;
        short hi, lo;
        split_bf16(v, hi, lo);
        fr[layer * 8192 + r] = (unsigned short)hi;
        fr[layer * 8192 + 4096 + r] = (unsigned short)lo;
    }
    // modulator layer-0 fragments (K=32 -> 2 k-steps)
    for (int e = tid; e < 2048; e += stride) {
        int el = e & 7, lane = (e >> 3) & 63, nt = (e >> 9) & 1, t = e >> 10;
        int k = t * 16 + (lane >> 5) * 8 + el;
        int n = nt * 32 + (lane & 31);
        short hi, lo;
        split_bf16(mw0[k * 64 + n], hi, lo);
        fr[MF_L0H + e] = (unsigned short)hi;
        fr[MF_L0L + e] = (unsigned short)lo;
    }
    // modulator layer-1/2 fragments (K=96 -> 6 k-steps)
    for (int e = tid; e < 6144; e += stride) {
        int el = e & 7, lane = (e >> 3) & 63, nt = (e >> 9) & 1, t = e >> 10;
        int k = t * 16 + (lane >> 5) * 8 + el;
        int n = nt * 32 + (lane & 31);
        short hi, lo;
        split_bf16(mw1[k * 64 + n], hi, lo);
        fr[MF_L1H + e] = (unsigned short)hi;
        fr[MF_L1L + e] = (unsigned short)lo;
        split_bf16(mw2[k * 64 + n], hi, lo);
        fr[MF_L2H + e] = (unsigned short)hi;
        fr[MF_L2L + e] = (unsigned short)lo;
    }
    // zero sort histogram
    for (int e = tid; e < NBINS; e += stride) counts[e] = 0;
}

// ---------------------------------------------------------------------------
// Sort kernels: counting sort of points by (batch, lo-cell).
// ---------------------------------------------------------------------------
__global__ void sort_hist(const float* __restrict__ x, int* __restrict__ counts) {
    int P = blockIdx.x * blockDim.x + threadIdx.x;
    if (P >= NPTS) return;
    atomicAdd(&counts[point_key(x, P)], 1);
}

__global__ __launch_bounds__(1024) void sort_scan(int* __restrict__ counts) {
    __shared__ int part[1024];
    int t = threadIdx.x;
    int base = t * (NBINS / 1024);
    int s = 0;
#pragma unroll 4
    for (int i = 0; i < NBINS / 1024; ++i) s += counts[base + i];
    part[t] = s;
    __syncthreads();
    for (int off = 1; off < 1024; off *= 2) {
        int v = (t >= off) ? part[t - off] : 0;
        __syncthreads();
        part[t] += v;
        __syncthreads();
    }
    int run = part[t] - s;
#pragma unroll 4
    for (int i = 0; i < NBINS / 1024; ++i) {
        int c = counts[base + i];
        counts[base + i] = run;
        run += c;
    }
}

__global__ void sort_scatter(const float* __restrict__ x,
                             int* __restrict__ counts,
                             float4* __restrict__ xs4) {
    int P = blockIdx.x * blockDim.x + threadIdx.x;
    if (P >= NPTS) return;
    int key = point_key(x, P);
    int pos = atomicAdd(&counts[key], 1);
    float4 v;
    v.x = x[P * 3 + 0]; v.y = x[P * 3 + 1]; v.z = x[P * 3 + 2];
    v.w = __int_as_float(P);
    xs4[pos] = v;
}

// ---------------------------------------------------------------------------
// Kernel 1: modulator precompute via MFMA. 4 waves/block, 32 cells/wave.
// D = W^T x LV per layer (split-bf16 3-pass); relu+bias in acc regs; y values
// stay lane-local (lane = cell) -> B-frags for the next layer built with the
// same shfl_xor(32) relayout as decode. Outputs stored as per-lane float4s.
// ---------------------------------------------------------------------------
#define RELAYOUT_SPLIT(accA, tb, bh, bl)                                   \
    {                                                                      \
        float fe[8];                                                       \
        _Pragma("unroll") for (int j = 0; j < 4; ++j) {                    \
            float uu = (accA)[(tb) * 8 + j];                               \
            float ww = (accA)[(tb) * 8 + 4 + j];                           \
            float send = hh ? uu : ww;                                     \
            float recv = __shfl_xor(send, 32);                             \
            fe[j] = hh ? recv : uu;                                        \
            fe[4 + j] = hh ? ww : recv;                                    \
        }                                                                  \
        _Pragma("unroll") for (int e = 0; e < 8; ++e) {                    \
            short sh, sl; split_trunc(fe[e], sh, sl);                      \
            (bh)[e] = sh; (bl)[e] = sl;                                    \
        }                                                                  \
    }

__global__ __launch_bounds__(256, 4) void mods_mfma(
        const float* __restrict__ lv,
        const float* __restrict__ mb0,
        const float* __restrict__ mb1,
        const float* __restrict__ mb2,
        float* __restrict__ ws) {
    const unsigned short* fr = (const unsigned short*)ws;
    float* table = ws + WS_TABLE;
    __shared__ float wb[192];

    int tid = threadIdx.x;
    int l = tid & 63, wv = tid >> 6;
    int p = l & 31, hh = l >> 5;
    if (tid < 64) wb[tid] = mb0[tid];
    else if (tid < 128) wb[tid] = mb1[tid - 64];
    else if (tid < 192) wb[tid] = mb2[tid - 128];
    __syncthreads();

    int tile = blockIdx.x * 4 + wv;       // 4096 tiles of 32 cells
    int C0 = tile * 32;
    int b = C0 >> 15;
    int cell0 = C0 & (G3 - 1);
    const float* lvb = lv + (((size_t)b * LAT) << 15) + cell0;

    // persistent lv B-frags (latent k-steps 0,1), split hi/lo
    bf16x8 lvh[2], lvl[2];
#pragma unroll
    for (int t2 = 0; t2 < 2; ++t2)
#pragma unroll
        for (int e = 0; e < 8; ++e) {
            float v = lvb[((size_t)(t2 * 16 + hh * 8 + e) << 15) + p];
            short sh, sl; split_trunc(v, sh, sl);
            lvh[t2][e] = sh; lvl[t2][e] = sl;
        }

    float* trow = table + (size_t)(C0 + p) * 192;

    // ================= layer 0: K=32 =================
    f32x16 a0 = {}, a1 = {};
#pragma unroll
    for (int t2 = 0; t2 < 2; ++t2) {
        bf16x8 ah0 = ((const bf16x8*)(fr + MF_L0H))[(t2 * 2 + 0) * 64 + l];
        bf16x8 ah1 = ((const bf16x8*)(fr + MF_L0H))[(t2 * 2 + 1) * 64 + l];
        bf16x8 al0 = ((const bf16x8*)(fr + MF_L0L))[(t2 * 2 + 0) * 64 + l];
        bf16x8 al1 = ((const bf16x8*)(fr + MF_L0L))[(t2 * 2 + 1) * 64 + l];
        a0 = MFMA32(ah0, lvh[t2], a0); a1 = MFMA32(ah1, lvh[t2], a1);
        a0 = MFMA32(ah0, lvl[t2], a0); a1 = MFMA32(ah1, lvl[t2], a1);
        a0 = MFMA32(al0, lvh[t2], a0); a1 = MFMA32(al1, lvh[t2], a1);
    }
    // bias + relu in-place, store mods0
#pragma unroll
    for (int nt = 0; nt < 2; ++nt) {
        f32x16& A = nt ? a1 : a0;
#pragma unroll
        for (int g = 0; g < 4; ++g) {
            int n0 = nt * 32 + g * 8 + hh * 4;
            float4 bia = *(const float4*)&wb[n0];
#pragma unroll
            for (int j = 0; j < 4; ++j)
                A[g * 4 + j] = fmaxf(A[g * 4 + j] + C4(bia, j), 0.f);
            *(float4*)&trow[n0] = make_float4(A[g * 4 + 0], A[g * 4 + 1], A[g * 4 + 2], A[g * 4 + 3]);
        }
    }

    // ================= layer 1: K=96 (y0 then lv) =================
    f32x16 c0 = {}, c1 = {};
#pragma unroll
    for (int t = 0; t < 4; ++t) {
        const f32x16& accA = (t < 2) ? a0 : a1;
        const int tb = t & 1;
        bf16x8 bh, bl;
        RELAYOUT_SPLIT(accA, tb, bh, bl);
        bf16x8 ah0 = ((const bf16x8*)(fr + MF_L1H))[(t * 2 + 0) * 64 + l];
        bf16x8 ah1 = ((const bf16x8*)(fr + MF_L1H))[(t * 2 + 1) * 64 + l];
        bf16x8 al0 = ((const bf16x8*)(fr + MF_L1L))[(t * 2 + 0) * 64 + l];
        bf16x8 al1 = ((const bf16x8*)(fr + MF_L1L))[(t * 2 + 1) * 64 + l];
        c0 = MFMA32(ah0, bh, c0); c1 = MFMA32(ah1, bh, c1);
        c0 = MFMA32(ah0, bl, c0); c1 = MFMA32(ah1, bl, c1);
        c0 = MFMA32(al0, bh, c0); c1 = MFMA32(al1, bh, c1);
    }
#pragma unroll
    for (int t2 = 0; t2 < 2; ++t2) {
        int t = 4 + t2;
        bf16x8 ah0 = ((const bf16x8*)(fr + MF_L1H))[(t * 2 + 0) * 64 + l];
        bf16x8 ah1 = ((const bf16x8*)(fr + MF_L1H))[(t * 2 + 1) * 64 + l];
        bf16x8 al0 = ((const bf16x8*)(fr + MF_L1L))[(t * 2 + 0) * 64 + l];
        bf16x8 al1 = ((const bf16x8*)(fr + MF_L1L))[(t * 2 + 1) * 64 + l];
        c0 = MFMA32(ah0, lvh[t2], c0); c1 = MFMA32(ah1, lvh[t2], c1);
        c0 = MFMA32(ah0, lvl[t2], c0); c1 = MFMA32(ah1, lvl[t2], c1);
        c0 = MFMA32(al0, lvh[t2], c0); c1 = MFMA32(al1, lvh[t2], c1);
    }
#pragma unroll
    for (int nt = 0; nt < 2; ++nt) {
        f32x16& A = nt ? c1 : c0;
#pragma unroll
        for (int g = 0; g < 4; ++g) {
            int n0 = nt * 32 + g * 8 + hh * 4;
            float4 bia = *(const float4*)&wb[64 + n0];
#pragma unroll
            for (int j = 0; j < 4; ++j)
                A[g * 4 + j] = fmaxf(A[g * 4 + j] + C4(bia, j), 0.f);
            *(float4*)&trow[64 + n0] = make_float4(A[g * 4 + 0], A[g * 4 + 1], A[g * 4 + 2], A[g * 4 + 3]);
        }
    }

    // ================= layer 2: K=96 (y1 then lv) =================
    f32x16 d0 = {}, d1 = {};
#pragma unroll
    for (int t = 0; t < 4; ++t) {
        const f32x16& accA = (t < 2) ? c0 : c1;
        const int tb = t & 1;
        bf16x8 bh, bl;
        RELAYOUT_SPLIT(accA, tb, bh, bl);
        bf16x8 ah0 = ((const bf16x8*)(fr + MF_L2H))[(t * 2 + 0) * 64 + l];
        bf16x8 ah1 = ((const bf16x8*)(fr + MF_L2H))[(t * 2 + 1) * 64 + l];
        bf16x8 al0 = ((const bf16x8*)(fr + MF_L2L))[(t * 2 + 0) * 64 + l];
        bf16x8 al1 = ((const bf16x8*)(fr + MF_L2L))[(t * 2 + 1) * 64 + l];
        d0 = MFMA32(ah0, bh, d0); d1 = MFMA32(ah1, bh, d1);
        d0 = MFMA32(ah0, bl, d0); d1 = MFMA32(ah1, bl, d1);
        d0 = MFMA32(al0, bh, d0); d1 = MFMA32(al1, bh, d1);
    }
#pragma unroll
    for (int t2 = 0; t2 < 2; ++t2) {
        int t = 4 + t2;
        bf16x8 ah0 = ((const bf16x8*)(fr + MF_L2H))[(t * 2 + 0) * 64 + l];
        bf16x8 ah1 = ((const bf16x8*)(fr + MF_L2H))[(t * 2 + 1) * 64 + l];
        bf16x8 al0 = ((const bf16x8*)(fr + MF_L2L))[(t * 2 + 0) * 64 + l];
        bf16x8 al1 = ((const bf16x8*)(fr + MF_L2L))[(t * 2 + 1) * 64 + l];
        d0 = MFMA32(ah0, lvh[t2], d0); d1 = MFMA32(ah1, lvh[t2], d1);
        d0 = MFMA32(ah0, lvl[t2], d0); d1 = MFMA32(ah1, lvl[t2], d1);
        d0 = MFMA32(al0, lvh[t2], d0); d1 = MFMA32(al1, lvh[t2], d1);
    }
#pragma unroll
    for (int nt = 0; nt < 2; ++nt) {
        f32x16& A = nt ? d1 : d0;
#pragma unroll
        for (int g = 0; g < 4; ++g) {
            int n0 = nt * 32 + g * 8 + hh * 4;
            float4 bia = *(const float4*)&wb[128 + n0];
#pragma unroll
            for (int j = 0; j < 4; ++j)
                A[g * 4 + j] = fmaxf(A[g * 4 + j] + C4(bia, j), 0.f);
            *(float4*)&trow[128 + n0] = make_float4(A[g * 4 + 0], A[g * 4 + 1], A[g * 4 + 2], A[g * 4 + 3]);
        }
    }
}

// ---------------------------------------------------------------------------
// Kernel 2: MFMA decode over cell-sorted points (as R6, VGPR forced <=64).
// ---------------------------------------------------------------------------
#define WAVES_PER_BLK 4
#define NBLK (NPTS / (32 * WAVES_PER_BLK))   // 3125
#define L_SW0 0
#define L_SB0 192
#define L_SB1 256
#define L_SB2 320
#define L_LW  384
#define L_WTOT 448

__global__ __launch_bounds__(256, 8) void decode_mfma(
        const float* __restrict__ ws,
        const float* __restrict__ sw0,
        const float* __restrict__ sb0,
        const float* __restrict__ sb1,
        const float* __restrict__ sb2,
        const float* __restrict__ lw,
        const float* __restrict__ lb,
        float* __restrict__ out) {
    const unsigned short* fr = (const unsigned short*)ws;
    const float* table = ws + WS_TABLE;
    const float4* xs4 = (const float4*)(ws + WS_XS4);

    __shared__ __align__(16) float wbuf[L_WTOT];

    int tid = threadIdx.x;
    int l = tid & 63;
    int wv = tid >> 6;
    int p = l & 31;
    int hh = l >> 5;

    for (int i = l; i < 192; i += 64) wbuf[L_SW0 + i] = sw0[i] * S0SCALE;
    wbuf[L_SB0 + l] = sb0[l] * S0SCALE;
    wbuf[L_SB1 + l] = sb1[l] * INV2PI;
    wbuf[L_SB2 + l] = sb2[l] * INV2PI;
    wbuf[L_LW + l]  = lw[l];
    __syncthreads();

    int orig = blockIdx.x;
    const int q8 = NBLK / 8, r8 = NBLK % 8;
    int xcd = orig & 7, pos = orig >> 3;
    int blk = (xcd < r8 ? xcd * (q8 + 1) : r8 * (q8 + 1) + (xcd - r8) * q8) + pos;
    int tile = blk * WAVES_PER_BLK + wv;

    float4 xp = xs4[tile * 32 + p];
    int P = __float_as_int(xp.w);
    int b = point_batch(P);

    float xg0 = xp.x * (float)GRD, xg1 = xp.y * (float)GRD, xg2 = xp.z * (float)GRD;
    int g00 = (int)(xg0 - 0.5f), g01 = (int)(xg1 - 0.5f), g02 = (int)(xg2 - 0.5f);
    int g10 = (int)(xg0 + 0.5f), g11 = (int)(xg1 + 0.5f), g12 = (int)(xg2 + 0.5f);
    int lo0 = min(max(g00, 0), GRD - 1), lo1 = min(max(g01, 0), GRD - 1), lo2 = min(max(g02, 0), GRD - 1);
    int hi0 = min(max(g10, 0), GRD - 1), hi1 = min(max(g11, 0), GRD - 1), hi2 = min(max(g12, 0), GRD - 1);
    float wx = xg0 - 0.5f - (float)g00;
    float wy = xg1 - 0.5f - (float)g01;
    float wz = xg2 - 0.5f - (float)g02;

    float accO = 0.f;

#pragma unroll 1
    for (int corner = 0; corner < 8; ++corner) {
        int ci = (corner >> 2) & 1, cj = (corner >> 1) & 1, ck = corner & 1;
        int c0 = ci ? hi0 : lo0, c1 = cj ? hi1 : lo1, c2 = ck ? hi2 : lo2;
        unsigned idx = (unsigned)((c0 * GRD + c1) * GRD + c2);
        float cw = (ci ? wx : 1.f - wx) * (cj ? wy : 1.f - wy) * (ck ? wz : 1.f - wz);
        float xi0 = xg0 - (float)c0 - 0.5f;
        float xi1 = xg1 - (float)c1 - 0.5f;
        float xi2 = xg2 - (float)c2 - 0.5f;

        const float* mrow = table + (size_t)(((unsigned)b << 15) | idx) * 192u;

        const unsigned short* frc = fr;
        asm volatile("" : "+s"(frc));
        const bf16x8* A1h = (const bf16x8*)(frc);
        const bf16x8* A1l = (const bf16x8*)(frc + 4096);
        const bf16x8* A2h = (const bf16x8*)(frc + 8192);
        const bf16x8* A2l = (const bf16x8*)(frc + 12288);

        f32x16 acc0 = {}, acc1 = {};
#pragma unroll
        for (int t = 0; t < 4; ++t) {
            const int nb = t * 16 + hh * 8;
            float4 w0a = *(const float4*)&wbuf[L_SW0 + nb],       w0b = *(const float4*)&wbuf[L_SW0 + nb + 4];
            float4 w1a = *(const float4*)&wbuf[L_SW0 + 64 + nb],  w1b = *(const float4*)&wbuf[L_SW0 + 64 + nb + 4];
            float4 w2a = *(const float4*)&wbuf[L_SW0 + 128 + nb], w2b = *(const float4*)&wbuf[L_SW0 + 128 + nb + 4];
            float4 bba = *(const float4*)&wbuf[L_SB0 + nb],       bbb = *(const float4*)&wbuf[L_SB0 + nb + 4];
            float4 m0a = *(const float4*)&mrow[nb],               m0b = *(const float4*)&mrow[nb + 4];

            float y[8];
            y[0] = sinrev(fmaf(xi0, w0a.x, fmaf(xi1, w1a.x, fmaf(xi2, w2a.x, bba.x)))) * m0a.x;
            y[1] = sinrev(fmaf(xi0, w0a.y, fmaf(xi1, w1a.y, fmaf(xi2, w2a.y, bba.y)))) * m0a.y;
            y[2] = sinrev(fmaf(xi0, w0a.z, fmaf(xi1, w1a.z, fmaf(xi2, w2a.z, bba.z)))) * m0a.z;
            y[3] = sinrev(fmaf(xi0, w0a.w, fmaf(xi1, w1a.w, fmaf(xi2, w2a.w, bba.w)))) * m0a.w;
            y[4] = sinrev(fmaf(xi0, w0b.x, fmaf(xi1, w1b.x, fmaf(xi2, w2b.x, bbb.x)))) * m0b.x;
            y[5] = sinrev(fmaf(xi0, w0b.y, fmaf(xi1, w1b.y, fmaf(xi2, w2b.y, bbb.y)))) * m0b.y;
            y[6] = sinrev(fmaf(xi0, w0b.z, fmaf(xi1, w1b.z, fmaf(xi2, w2b.z, bbb.z)))) * m0b.z;
            y[7] = sinrev(fmaf(xi0, w0b.w, fmaf(xi1, w1b.w, fmaf(xi2, w2b.w, bbb.w)))) * m0b.w;

            bf16x8 bh, bl;
#pragma unroll
            for (int e = 0; e < 8; ++e) { short sh, sl; split_trunc(y[e], sh, sl); bh[e] = sh; bl[e] = sl; }

            bf16x8 ah0 = A1h[(t * 2 + 0) * 64 + l], al0 = A1l[(t * 2 + 0) * 64 + l];
            bf16x8 ah1 = A1h[(t * 2 + 1) * 64 + l], al1 = A1l[(t * 2 + 1) * 64 + l];
            acc0 = MFMA32(ah0, bh, acc0);
            acc1 = MFMA32(ah1, bh, acc1);
            acc0 = MFMA32(ah0, bl, acc0);
            acc1 = MFMA32(ah1, bl, acc1);
            acc0 = MFMA32(al0, bh, acc0);
            acc1 = MFMA32(al1, bh, acc1);
        }

        f32x16 ac20 = {}, ac21 = {};
#pragma unroll
        for (int t = 0; t < 4; ++t) {
            const f32x16& accA = (t < 2) ? acc0 : acc1;
            const int tb = t & 1;
            float4 bia_u = *(const float4*)&wbuf[L_SB1 + t * 16 + hh * 4];
            float4 bia_w = *(const float4*)&wbuf[L_SB1 + t * 16 + 8 + hh * 4];
            float4 mo_u  = *(const float4*)&mrow[64 + t * 16 + hh * 4];
            float4 mo_w  = *(const float4*)&mrow[64 + t * 16 + 8 + hh * 4];

            float fe[8];
#pragma unroll
            for (int j = 0; j < 4; ++j) {
                float uu = sinrev(accA[tb * 8 + j]     + C4(bia_u, j)) * C4(mo_u, j);
                float ww = sinrev(accA[tb * 8 + 4 + j] + C4(bia_w, j)) * C4(mo_w, j);
                float send = hh ? uu : ww;
                float recv = __shfl_xor(send, 32);
                fe[j]     = hh ? recv : uu;
                fe[4 + j] = hh ? ww : recv;
            }

            bf16x8 bh, bl;
#pragma unroll
            for (int e = 0; e < 8; ++e) { short sh, sl; split_trunc(fe[e], sh, sl); bh[e] = sh; bl[e] = sl; }

            bf16x8 ah0 = A2h[(t * 2 + 0) * 64 + l], al0 = A2l[(t * 2 + 0) * 64 + l];
            bf16x8 ah1 = A2h[(t * 2 + 1) * 64 + l], al1 = A2l[(t * 2 + 1) * 64 + l];
            ac20 = MFMA32(ah0, bh, ac20);
            ac21 = MFMA32(ah1, bh, ac21);
            ac20 = MFMA32(ah0, bl, ac20);
            ac21 = MFMA32(ah1, bl, ac21);
            ac20 = MFMA32(al0, bh, ac20);
            ac21 = MFMA32(al1, bh, ac21);
        }

        float dot = 0.f;
#pragma unroll
        for (int nt = 0; nt < 2; ++nt) {
#pragma unroll
            for (int g = 0; g < 4; ++g) {
                int n = nt * 32 + g * 8 + hh * 4;
                float4 bia = *(const float4*)&wbuf[L_SB2 + n];
                float4 mo  = *(const float4*)&mrow[128 + n];
                float4 lwv = *(const float4*)&wbuf[L_LW + n];
                float v0, v1, v2, v3;
                if (nt == 0) {
                    v0 = ac20[g * 4 + 0]; v1 = ac20[g * 4 + 1]; v2 = ac20[g * 4 + 2]; v3 = ac20[g * 4 + 3];
                } else {
                    v0 = ac21[g * 4 + 0]; v1 = ac21[g * 4 + 1]; v2 = ac21[g * 4 + 2]; v3 = ac21[g * 4 + 3];
                }
                dot = fmaf(sinrev(v0 + bia.x) * mo.x, lwv.x, dot);
                dot = fmaf(sinrev(v1 + bia.y) * mo.y, lwv.y, dot);
                dot = fmaf(sinrev(v2 + bia.z) * mo.z, lwv.z, dot);
                dot = fmaf(sinrev(v3 + bia.w) * mo.w, lwv.w, dot);
            }
        }
        dot += __shfl_xor(dot, 32);
        accO = fmaf(cw, dot + lb[0], accO);
    }

    if (hh == 0) out[P] = accO;
}

// ---------------------------------------------------------------------------
// Fallback: fully inline, one thread per point (only if ws too small).
// ---------------------------------------------------------------------------
__global__ void naive_decode(
        const float* __restrict__ x, const float* __restrict__ lv,
        const float* __restrict__ mw0, const float* __restrict__ mb0,
        const float* __restrict__ mw1, const float* __restrict__ mb1,
        const float* __restrict__ mw2, const float* __restrict__ mb2,
        const float* __restrict__ sw0, const float* __restrict__ sb0,
        const float* __restrict__ sw1, const float* __restrict__ sb1,
        const float* __restrict__ sw2, const float* __restrict__ sb2,
        const float* __restrict__ lw, const float* __restrict__ lb,
        float* __restrict__ out) {
    int P = blockIdx.x * blockDim.x + threadIdx.x;
    if (P >= NPTS) return;
    int b = P / NPER;
    float xs[3] = {x[P * 3 + 0], x[P * 3 + 1], x[P * 3 + 2]};
    float xg[3] = {xs[0] * 32.f, xs[1] * 32.f, xs[2] * 32.f};
    int lo[3], hi[3]; float lrp[3];
    for (int d = 0; d < 3; ++d) {
        int g0 = (int)(xg[d] - 0.5f), g1 = (int)(xg[d] + 0.5f);
        lo[d] = min(max(g0, 0), 31); hi[d] = min(max(g1, 0), 31);
        lrp[d] = xg[d] - 0.5f - (float)g0;
    }
    float acc = 0.f;
    for (int corner = 0; corner < 8; ++corner) {
        int ci = (corner >> 2) & 1, cj = (corner >> 1) & 1, ck = corner & 1;
        int c0 = ci ? hi[0] : lo[0], c1 = cj ? hi[1] : lo[1], c2 = ck ? hi[2] : lo[2];
        int idx = (c0 * 32 + c1) * 32 + c2;
        float cw = (ci ? lrp[0] : 1.f - lrp[0]) * (cj ? lrp[1] : 1.f - lrp[1]) * (ck ? lrp[2] : 1.f - lrp[2]);
        float xi0 = xg[0] - c0 - 0.5f, xi1 = xg[1] - c1 - 0.5f, xi2 = xg[2] - c2 - 0.5f;
        float lvv[32];
        for (int f = 0; f < 32; ++f) lvv[f] = lv[((size_t)(b * 32 + f) << 15) + idx];
        float m0[64], m1[64], m2[64];
        for (int j = 0; j < 64; ++j) { float s = mb0[j]; for (int i = 0; i < 32; ++i) s = fmaf(lvv[i], mw0[i * 64 + j], s); m0[j] = fmaxf(s, 0.f); }
        for (int j = 0; j < 64; ++j) { float s = mb1[j]; for (int i = 0; i < 64; ++i) s = fmaf(m0[i], mw1[i * 64 + j], s); for (int i = 0; i < 32; ++i) s = fmaf(lvv[i], mw1[(64 + i) * 64 + j], s); m1[j] = fmaxf(s, 0.f); }
        for (int j = 0; j < 64; ++j) { float s = mb2[j]; for (int i = 0; i < 64; ++i) s = fmaf(m1[i], mw2[i * 64 + j], s); for (int i = 0; i < 32; ++i) s = fmaf(lvv[i], mw2[(64 + i) * 64 + j], s); m2[j] = fmaxf(s, 0.f); }
        float s0[64];
        for (int j = 0; j < 64; ++j) s0[j] = __sinf(30.f * fmaf(xi0, sw0[j], fmaf(xi1, sw0[64 + j], fmaf(xi2, sw0[128 + j], sb0[j])))) * m0[j];
        float s1[64];
        for (int j = 0; j < 64; ++j) { float s = sb1[j]; for (int i = 0; i < 64; ++i) s = fmaf(s0[i], sw1[i * 64 + j], s); s1[j] = __sinf(s) * m1[j]; }
        float s2[64];
        for (int j = 0; j < 64; ++j) { float s = sb2[j]; for (int i = 0; i < 64; ++i) s = fmaf(s1[i], sw2[i * 64 + j], s); s2[j] = __sinf(s) * m2[j]; }
        float dot = lb[0];
        for (int i = 0; i < 64; ++i) dot = fmaf(s2[i], lw[i], dot);
        acc = fmaf(cw, dot, acc);
    }
    out[P] = acc;
}

extern "C" void kernel_launch(void* const* d_in, const int* in_sizes, int n_in,
                              void* d_out, int out_size, void* d_ws, size_t ws_size,
                              hipStream_t stream) {
    const float* x   = (const float*)d_in[0];
    const float* lv  = (const float*)d_in[1];
    const float* mw0 = (const float*)d_in[2];
    const float* mb0 = (const float*)d_in[3];
    const float* mw1 = (const float*)d_in[4];
    const float* mb1 = (const float*)d_in[5];
    const float* mw2 = (const float*)d_in[6];
    const float* mb2 = (const float*)d_in[7];
    const float* sw0 = (const float*)d_in[8];
    const float* sb0 = (const float*)d_in[9];
    const float* sw1 = (const float*)d_in[10];
    const float* sb1 = (const float*)d_in[11];
    const float* sw2 = (const float*)d_in[12];
    const float* sb2 = (const float*)d_in[13];
    const float* lw  = (const float*)d_in[14];
    const float* lb  = (const float*)d_in[15];
    float* out = (float*)d_out;
    float* ws  = (float*)d_ws;

    if (ws_size >= WS_NEEDED_BYTES) {
        int* counts = (int*)(ws + WS_COUNTS);
        float4* xs4 = (float4*)(ws + WS_XS4);
        prep_pack<<<64, 256, 0, stream>>>(sw1, sw2, mw0, mw1, mw2, ws, counts);
        sort_hist<<<(NPTS + 255) / 256, 256, 0, stream>>>(x, counts);
        sort_scan<<<1, 1024, 0, stream>>>(counts);
        sort_scatter<<<(NPTS + 255) / 256, 256, 0, stream>>>(x, counts, xs4);
        mods_mfma<<<NBINS / 128, 256, 0, stream>>>(lv, mb0, mb1, mb2, ws);
        decode_mfma<<<NBLK, 256, 0, stream>>>(
            ws, sw0, sb0, sb1, sb2, lw, lb, out);
    } else {
        naive_decode<<<(NPTS + 255) / 256, 256, 0, stream>>>(
            x, lv, mw0, mb0, mw1, mb1, mw2, mb2, sw0, sb0, sw1, sb1, sw2, sb2, lw, lb, out);
    }
}

// Round 8
// 396.781 us; speedup vs baseline: 4.0932x; 4.0932x over previous
//
#include <hip/hip_runtime.h>
#include <hip/hip_bf16.h>

// Problem constants
#define BATCH   4
#define NPER    100000
#define NPTS    (BATCH * NPER)     // 400000
#define GRD     32
#define G3      32768
#define LAT     32
#define HID     64
#define NBINS   (BATCH * G3)       // 131072

#define INV2PI 0.15915494309189535f
#define S0SCALE (30.0f * INV2PI)

// Workspace layout (float offsets)
#define WS_TABLE 32768
#define TABLE_FLOATS ((size_t)NBINS * 192)
#define WS_COUNTS (WS_TABLE + TABLE_FLOATS)
#define WS_XS4    (WS_COUNTS + NBINS)
#define WS_TOTAL  (WS_XS4 + (size_t)NPTS * 4)
#define WS_NEEDED_BYTES ((size_t)WS_TOTAL * 4)       // ~107.7 MB

// modulator A-frag ushort offsets
#define MF_L0H 16384
#define MF_L0L 18432
#define MF_L1H 20480
#define MF_L1L 26624
#define MF_L2H 32768
#define MF_L2L 38912

typedef short bf16x8 __attribute__((ext_vector_type(8)));
typedef float f32x16 __attribute__((ext_vector_type(16)));

#define C4(v, j) ((j) == 0 ? (v).x : (j) == 1 ? (v).y : (j) == 2 ? (v).z : (v).w)
#define MFMA32(a, b, c) __builtin_amdgcn_mfma_f32_32x32x16_bf16((a), (b), (c), 0, 0, 0)

__device__ __forceinline__ void split_bf16(float v, short& hi, short& lo) {
    __hip_bfloat16 hb = __float2bfloat16(v);
    float hf = __bfloat162float(hb);
    __hip_bfloat16 lb2 = __float2bfloat16(v - hf);
    hi = *(short*)&hb;
    lo = *(short*)&lb2;
}

// cheap truncation split (error compensated by the 3-pass MFMA)
__device__ __forceinline__ void split_trunc(float v, short& hi, short& lo) {
    unsigned u = __float_as_uint(v);
    unsigned hu = u & 0xffff0000u;
    float lof = v - __uint_as_float(hu);
    hi = (short)(hu >> 16);
    lo = (short)(__float_as_uint(lof) >> 16);
}

// sin(2*pi*t), any t
__device__ __forceinline__ float sinrev(float t) {
    return __builtin_amdgcn_sinf(__builtin_amdgcn_fractf(t));
}

__device__ __forceinline__ int point_batch(int P) {
    return (P >= NPER) + (P >= 2 * NPER) + (P >= 3 * NPER);
}

__device__ __forceinline__ int point_key(const float* __restrict__ x, int P) {
    float xg0 = x[P * 3 + 0] * (float)GRD;
    float xg1 = x[P * 3 + 1] * (float)GRD;
    float xg2 = x[P * 3 + 2] * (float)GRD;
    int l0 = min(max((int)(xg0 - 0.5f), 0), GRD - 1);
    int l1 = min(max((int)(xg1 - 0.5f), 0), GRD - 1);
    int l2 = min(max((int)(xg2 - 0.5f), 0), GRD - 1);
    return (point_batch(P) << 15) | ((l0 * GRD + l1) * GRD + l2);
}

// ---------------------------------------------------------------------------
// Kernel 0: pack all MFMA A-fragment tables + zero the sort histogram.
// ---------------------------------------------------------------------------
__global__ void prep_pack(const float* __restrict__ sw1,
                          const float* __restrict__ sw2,
                          const float* __restrict__ mw0,
                          const float* __restrict__ mw1,
                          const float* __restrict__ mw2,
                          float* __restrict__ ws,
                          int* __restrict__ counts) {
    int tid = threadIdx.x + blockIdx.x * blockDim.x;
    int stride = blockDim.x * gridDim.x;
    unsigned short* fr = (unsigned short*)ws;

    // siren layer-1/2 fragments (scaled 1/2pi)
    for (int e = tid; e < 8192; e += stride) {
        int layer = e >> 12;
        int r = e & 4095;
        int el = r & 7;
        int lane = (r >> 3) & 63;
        int nt = (r >> 9) & 1;
        int t = r >> 10;
        int k = t * 16 + (lane >> 5) * 8 + el;
        int n = nt * 32 + (lane & 31);
        const float* w = layer ? sw2 : sw1;
        float v = w[k * 64 + n] * INV2PI;
        short hi, lo;
        split_bf16(v, hi, lo);
        fr[layer * 8192 + r] = (unsigned short)hi;
        fr[layer * 8192 + 4096 + r] = (unsigned short)lo;
    }
    // modulator layer-0 fragments (K=32 -> 2 k-steps)
    for (int e = tid; e < 2048; e += stride) {
        int el = e & 7, lane = (e >> 3) & 63, nt = (e >> 9) & 1, t = e >> 10;
        int k = t * 16 + (lane >> 5) * 8 + el;
        int n = nt * 32 + (lane & 31);
        short hi, lo;
        split_bf16(mw0[k * 64 + n], hi, lo);
        fr[MF_L0H + e] = (unsigned short)hi;
        fr[MF_L0L + e] = (unsigned short)lo;
    }
    // modulator layer-1/2 fragments (K=96 -> 6 k-steps)
    for (int e = tid; e < 6144; e += stride) {
        int el = e & 7, lane = (e >> 3) & 63, nt = (e >> 9) & 1, t = e >> 10;
        int k = t * 16 + (lane >> 5) * 8 + el;
        int n = nt * 32 + (lane & 31);
        short hi, lo;
        split_bf16(mw1[k * 64 + n], hi, lo);
        fr[MF_L1H + e] = (unsigned short)hi;
        fr[MF_L1L + e] = (unsigned short)lo;
        split_bf16(mw2[k * 64 + n], hi, lo);
        fr[MF_L2H + e] = (unsigned short)hi;
        fr[MF_L2L + e] = (unsigned short)lo;
    }
    // zero sort histogram
    for (int e = tid; e < NBINS; e += stride) counts[e] = 0;
}

// ---------------------------------------------------------------------------
// Sort kernels: counting sort of points by (batch, lo-cell).
// ---------------------------------------------------------------------------
__global__ void sort_hist(const float* __restrict__ x, int* __restrict__ counts) {
    int P = blockIdx.x * blockDim.x + threadIdx.x;
    if (P >= NPTS) return;
    atomicAdd(&counts[point_key(x, P)], 1);
}

__global__ __launch_bounds__(1024) void sort_scan(int* __restrict__ counts) {
    __shared__ int part[1024];
    int t = threadIdx.x;
    int base = t * (NBINS / 1024);
    int s = 0;
#pragma unroll 4
    for (int i = 0; i < NBINS / 1024; ++i) s += counts[base + i];
    part[t] = s;
    __syncthreads();
    for (int off = 1; off < 1024; off *= 2) {
        int v = (t >= off) ? part[t - off] : 0;
        __syncthreads();
        part[t] += v;
        __syncthreads();
    }
    int run = part[t] - s;
#pragma unroll 4
    for (int i = 0; i < NBINS / 1024; ++i) {
        int c = counts[base + i];
        counts[base + i] = run;
        run += c;
    }
}

__global__ void sort_scatter(const float* __restrict__ x,
                             int* __restrict__ counts,
                             float4* __restrict__ xs4) {
    int P = blockIdx.x * blockDim.x + threadIdx.x;
    if (P >= NPTS) return;
    int key = point_key(x, P);
    int pos = atomicAdd(&counts[key], 1);
    float4 v;
    v.x = x[P * 3 + 0]; v.y = x[P * 3 + 1]; v.z = x[P * 3 + 2];
    v.w = __int_as_float(P);
    xs4[pos] = v;
}

// ---------------------------------------------------------------------------
// Kernel 1: modulator precompute via MFMA. 4 waves/block, 32 cells/wave.
// ---------------------------------------------------------------------------
#define RELAYOUT_SPLIT(accA, tb, bh, bl)                                   \
    {                                                                      \
        float fe[8];                                                       \
        _Pragma("unroll") for (int j = 0; j < 4; ++j) {                    \
            float uu = (accA)[(tb) * 8 + j];                               \
            float ww = (accA)[(tb) * 8 + 4 + j];                           \
            float send = hh ? uu : ww;                                     \
            float recv = __shfl_xor(send, 32);                             \
            fe[j] = hh ? recv : uu;                                        \
            fe[4 + j] = hh ? ww : recv;                                    \
        }                                                                  \
        _Pragma("unroll") for (int e = 0; e < 8; ++e) {                    \
            short sh, sl; split_trunc(fe[e], sh, sl);                      \
            (bh)[e] = sh; (bl)[e] = sl;                                    \
        }                                                                  \
    }

__global__ __launch_bounds__(256, 4) void mods_mfma(
        const float* __restrict__ lv,
        const float* __restrict__ mb0,
        const float* __restrict__ mb1,
        const float* __restrict__ mb2,
        float* __restrict__ ws) {
    const unsigned short* fr = (const unsigned short*)ws;
    float* table = ws + WS_TABLE;
    __shared__ float wb[192];

    int tid = threadIdx.x;
    int l = tid & 63, wv = tid >> 6;
    int p = l & 31, hh = l >> 5;
    if (tid < 64) wb[tid] = mb0[tid];
    else if (tid < 128) wb[tid] = mb1[tid - 64];
    else if (tid < 192) wb[tid] = mb2[tid - 128];
    __syncthreads();

    int tile = blockIdx.x * 4 + wv;       // 4096 tiles of 32 cells
    int C0 = tile * 32;
    int b = C0 >> 15;
    int cell0 = C0 & (G3 - 1);
    const float* lvb = lv + (((size_t)b * LAT) << 15) + cell0;

    // persistent lv B-frags (latent k-steps 0,1), split hi/lo
    bf16x8 lvh[2], lvl[2];
#pragma unroll
    for (int t2 = 0; t2 < 2; ++t2)
#pragma unroll
        for (int e = 0; e < 8; ++e) {
            float v = lvb[((size_t)(t2 * 16 + hh * 8 + e) << 15) + p];
            short sh, sl; split_trunc(v, sh, sl);
            lvh[t2][e] = sh; lvl[t2][e] = sl;
        }

    float* trow = table + (size_t)(C0 + p) * 192;

    // ================= layer 0: K=32 =================
    f32x16 a0 = {}, a1 = {};
#pragma unroll
    for (int t2 = 0; t2 < 2; ++t2) {
        bf16x8 ah0 = ((const bf16x8*)(fr + MF_L0H))[(t2 * 2 + 0) * 64 + l];
        bf16x8 ah1 = ((const bf16x8*)(fr + MF_L0H))[(t2 * 2 + 1) * 64 + l];
        bf16x8 al0 = ((const bf16x8*)(fr + MF_L0L))[(t2 * 2 + 0) * 64 + l];
        bf16x8 al1 = ((const bf16x8*)(fr + MF_L0L))[(t2 * 2 + 1) * 64 + l];
        a0 = MFMA32(ah0, lvh[t2], a0); a1 = MFMA32(ah1, lvh[t2], a1);
        a0 = MFMA32(ah0, lvl[t2], a0); a1 = MFMA32(ah1, lvl[t2], a1);
        a0 = MFMA32(al0, lvh[t2], a0); a1 = MFMA32(al1, lvh[t2], a1);
    }
#pragma unroll
    for (int nt = 0; nt < 2; ++nt) {
        f32x16& A = nt ? a1 : a0;
#pragma unroll
        for (int g = 0; g < 4; ++g) {
            int n0 = nt * 32 + g * 8 + hh * 4;
            float4 bia = *(const float4*)&wb[n0];
#pragma unroll
            for (int j = 0; j < 4; ++j)
                A[g * 4 + j] = fmaxf(A[g * 4 + j] + C4(bia, j), 0.f);
            *(float4*)&trow[n0] = make_float4(A[g * 4 + 0], A[g * 4 + 1], A[g * 4 + 2], A[g * 4 + 3]);
        }
    }

    // ================= layer 1: K=96 (y0 then lv) =================
    f32x16 c0 = {}, c1 = {};
#pragma unroll
    for (int t = 0; t < 4; ++t) {
        const f32x16& accA = (t < 2) ? a0 : a1;
        const int tb = t & 1;
        bf16x8 bh, bl;
        RELAYOUT_SPLIT(accA, tb, bh, bl);
        bf16x8 ah0 = ((const bf16x8*)(fr + MF_L1H))[(t * 2 + 0) * 64 + l];
        bf16x8 ah1 = ((const bf16x8*)(fr + MF_L1H))[(t * 2 + 1) * 64 + l];
        bf16x8 al0 = ((const bf16x8*)(fr + MF_L1L))[(t * 2 + 0) * 64 + l];
        bf16x8 al1 = ((const bf16x8*)(fr + MF_L1L))[(t * 2 + 1) * 64 + l];
        c0 = MFMA32(ah0, bh, c0); c1 = MFMA32(ah1, bh, c1);
        c0 = MFMA32(ah0, bl, c0); c1 = MFMA32(ah1, bl, c1);
        c0 = MFMA32(al0, bh, c0); c1 = MFMA32(al1, bh, c1);
    }
#pragma unroll
    for (int t2 = 0; t2 < 2; ++t2) {
        int t = 4 + t2;
        bf16x8 ah0 = ((const bf16x8*)(fr + MF_L1H))[(t * 2 + 0) * 64 + l];
        bf16x8 ah1 = ((const bf16x8*)(fr + MF_L1H))[(t * 2 + 1) * 64 + l];
        bf16x8 al0 = ((const bf16x8*)(fr + MF_L1L))[(t * 2 + 0) * 64 + l];
        bf16x8 al1 = ((const bf16x8*)(fr + MF_L1L))[(t * 2 + 1) * 64 + l];
        c0 = MFMA32(ah0, lvh[t2], c0); c1 = MFMA32(ah1, lvh[t2], c1);
        c0 = MFMA32(ah0, lvl[t2], c0); c1 = MFMA32(ah1, lvl[t2], c1);
        c0 = MFMA32(al0, lvh[t2], c0); c1 = MFMA32(al1, lvh[t2], c1);
    }
#pragma unroll
    for (int nt = 0; nt < 2; ++nt) {
        f32x16& A = nt ? c1 : c0;
#pragma unroll
        for (int g = 0; g < 4; ++g) {
            int n0 = nt * 32 + g * 8 + hh * 4;
            float4 bia = *(const float4*)&wb[64 + n0];
#pragma unroll
            for (int j = 0; j < 4; ++j)
                A[g * 4 + j] = fmaxf(A[g * 4 + j] + C4(bia, j), 0.f);
            *(float4*)&trow[64 + n0] = make_float4(A[g * 4 + 0], A[g * 4 + 1], A[g * 4 + 2], A[g * 4 + 3]);
        }
    }

    // ================= layer 2: K=96 (y1 then lv) =================
    f32x16 d0 = {}, d1 = {};
#pragma unroll
    for (int t = 0; t < 4; ++t) {
        const f32x16& accA = (t < 2) ? c0 : c1;
        const int tb = t & 1;
        bf16x8 bh, bl;
        RELAYOUT_SPLIT(accA, tb, bh, bl);
        bf16x8 ah0 = ((const bf16x8*)(fr + MF_L2H))[(t * 2 + 0) * 64 + l];
        bf16x8 ah1 = ((const bf16x8*)(fr + MF_L2H))[(t * 2 + 1) * 64 + l];
        bf16x8 al0 = ((const bf16x8*)(fr + MF_L2L))[(t * 2 + 0) * 64 + l];
        bf16x8 al1 = ((const bf16x8*)(fr + MF_L2L))[(t * 2 + 1) * 64 + l];
        d0 = MFMA32(ah0, bh, d0); d1 = MFMA32(ah1, bh, d1);
        d0 = MFMA32(ah0, bl, d0); d1 = MFMA32(ah1, bl, d1);
        d0 = MFMA32(al0, bh, d0); d1 = MFMA32(al1, bh, d1);
    }
#pragma unroll
    for (int t2 = 0; t2 < 2; ++t2) {
        int t = 4 + t2;
        bf16x8 ah0 = ((const bf16x8*)(fr + MF_L2H))[(t * 2 + 0) * 64 + l];
        bf16x8 ah1 = ((const bf16x8*)(fr + MF_L2H))[(t * 2 + 1) * 64 + l];
        bf16x8 al0 = ((const bf16x8*)(fr + MF_L2L))[(t * 2 + 0) * 64 + l];
        bf16x8 al1 = ((const bf16x8*)(fr + MF_L2L))[(t * 2 + 1) * 64 + l];
        d0 = MFMA32(ah0, lvh[t2], d0); d1 = MFMA32(ah1, lvh[t2], d1);
        d0 = MFMA32(ah0, lvl[t2], d0); d1 = MFMA32(ah1, lvl[t2], d1);
        d0 = MFMA32(al0, lvh[t2], d0); d1 = MFMA32(al1, lvh[t2], d1);
    }
#pragma unroll
    for (int nt = 0; nt < 2; ++nt) {
        f32x16& A = nt ? d1 : d0;
#pragma unroll
        for (int g = 0; g < 4; ++g) {
            int n0 = nt * 32 + g * 8 + hh * 4;
            float4 bia = *(const float4*)&wb[128 + n0];
#pragma unroll
            for (int j = 0; j < 4; ++j)
                A[g * 4 + j] = fmaxf(A[g * 4 + j] + C4(bia, j), 0.f);
            *(float4*)&trow[128 + n0] = make_float4(A[g * 4 + 0], A[g * 4 + 1], A[g * 4 + 2], A[g * 4 + 3]);
        }
    }
}

// ---------------------------------------------------------------------------
// Kernel 2: MFMA decode over cell-sorted points.
// R6's proven config: (256,3), VGPR~68, zero spills. Do NOT force 8 waves —
// peak live set (~100-130 regs incl. 4x f32x16 accs) spills below 128.
// ---------------------------------------------------------------------------
#define WAVES_PER_BLK 4
#define NBLK (NPTS / (32 * WAVES_PER_BLK))   // 3125
#define L_SW0 0
#define L_SB0 192
#define L_SB1 256
#define L_SB2 320
#define L_LW  384
#define L_WTOT 448

__global__ __launch_bounds__(256, 3) void decode_mfma(
        const float* __restrict__ ws,
        const float* __restrict__ sw0,
        const float* __restrict__ sb0,
        const float* __restrict__ sb1,
        const float* __restrict__ sb2,
        const float* __restrict__ lw,
        const float* __restrict__ lb,
        float* __restrict__ out) {
    const unsigned short* fr = (const unsigned short*)ws;
    const float* table = ws + WS_TABLE;
    const float4* xs4 = (const float4*)(ws + WS_XS4);

    __shared__ __align__(16) float wbuf[L_WTOT];

    int tid = threadIdx.x;
    int l = tid & 63;
    int wv = tid >> 6;
    int p = l & 31;
    int hh = l >> 5;

    for (int i = l; i < 192; i += 64) wbuf[L_SW0 + i] = sw0[i] * S0SCALE;
    wbuf[L_SB0 + l] = sb0[l] * S0SCALE;
    wbuf[L_SB1 + l] = sb1[l] * INV2PI;
    wbuf[L_SB2 + l] = sb2[l] * INV2PI;
    wbuf[L_LW + l]  = lw[l];
    __syncthreads();

    int orig = blockIdx.x;
    const int q8 = NBLK / 8, r8 = NBLK % 8;
    int xcd = orig & 7, pos = orig >> 3;
    int blk = (xcd < r8 ? xcd * (q8 + 1) : r8 * (q8 + 1) + (xcd - r8) * q8) + pos;
    int tile = blk * WAVES_PER_BLK + wv;

    float4 xp = xs4[tile * 32 + p];
    int P = __float_as_int(xp.w);
    int b = point_batch(P);

    float xg0 = xp.x * (float)GRD, xg1 = xp.y * (float)GRD, xg2 = xp.z * (float)GRD;
    int g00 = (int)(xg0 - 0.5f), g01 = (int)(xg1 - 0.5f), g02 = (int)(xg2 - 0.5f);
    int g10 = (int)(xg0 + 0.5f), g11 = (int)(xg1 + 0.5f), g12 = (int)(xg2 + 0.5f);
    int lo0 = min(max(g00, 0), GRD - 1), lo1 = min(max(g01, 0), GRD - 1), lo2 = min(max(g02, 0), GRD - 1);
    int hi0 = min(max(g10, 0), GRD - 1), hi1 = min(max(g11, 0), GRD - 1), hi2 = min(max(g12, 0), GRD - 1);
    float wx = xg0 - 0.5f - (float)g00;
    float wy = xg1 - 0.5f - (float)g01;
    float wz = xg2 - 0.5f - (float)g02;

    float accO = 0.f;

#pragma unroll 1
    for (int corner = 0; corner < 8; ++corner) {
        int ci = (corner >> 2) & 1, cj = (corner >> 1) & 1, ck = corner & 1;
        int c0 = ci ? hi0 : lo0, c1 = cj ? hi1 : lo1, c2 = ck ? hi2 : lo2;
        unsigned idx = (unsigned)((c0 * GRD + c1) * GRD + c2);
        float cw = (ci ? wx : 1.f - wx) * (cj ? wy : 1.f - wy) * (ck ? wz : 1.f - wz);
        float xi0 = xg0 - (float)c0 - 0.5f;
        float xi1 = xg1 - (float)c1 - 0.5f;
        float xi2 = xg2 - (float)c2 - 0.5f;

        const float* mrow = table + (size_t)(((unsigned)b << 15) | idx) * 192u;

        const unsigned short* frc = fr;
        asm volatile("" : "+s"(frc));
        const bf16x8* A1h = (const bf16x8*)(frc);
        const bf16x8* A1l = (const bf16x8*)(frc + 4096);
        const bf16x8* A2h = (const bf16x8*)(frc + 8192);
        const bf16x8* A2l = (const bf16x8*)(frc + 12288);

        f32x16 acc0 = {}, acc1 = {};
#pragma unroll
        for (int t = 0; t < 4; ++t) {
            const int nb = t * 16 + hh * 8;
            float4 w0a = *(const float4*)&wbuf[L_SW0 + nb],       w0b = *(const float4*)&wbuf[L_SW0 + nb + 4];
            float4 w1a = *(const float4*)&wbuf[L_SW0 + 64 + nb],  w1b = *(const float4*)&wbuf[L_SW0 + 64 + nb + 4];
            float4 w2a = *(const float4*)&wbuf[L_SW0 + 128 + nb], w2b = *(const float4*)&wbuf[L_SW0 + 128 + nb + 4];
            float4 bba = *(const float4*)&wbuf[L_SB0 + nb],       bbb = *(const float4*)&wbuf[L_SB0 + nb + 4];
            float4 m0a = *(const float4*)&mrow[nb],               m0b = *(const float4*)&mrow[nb + 4];

            float y[8];
            y[0] = sinrev(fmaf(xi0, w0a.x, fmaf(xi1, w1a.x, fmaf(xi2, w2a.x, bba.x)))) * m0a.x;
            y[1] = sinrev(fmaf(xi0, w0a.y, fmaf(xi1, w1a.y, fmaf(xi2, w2a.y, bba.y)))) * m0a.y;
            y[2] = sinrev(fmaf(xi0, w0a.z, fmaf(xi1, w1a.z, fmaf(xi2, w2a.z, bba.z)))) * m0a.z;
            y[3] = sinrev(fmaf(xi0, w0a.w, fmaf(xi1, w1a.w, fmaf(xi2, w2a.w, bba.w)))) * m0a.w;
            y[4] = sinrev(fmaf(xi0, w0b.x, fmaf(xi1, w1b.x, fmaf(xi2, w2b.x, bbb.x)))) * m0b.x;
            y[5] = sinrev(fmaf(xi0, w0b.y, fmaf(xi1, w1b.y, fmaf(xi2, w2b.y, bbb.y)))) * m0b.y;
            y[6] = sinrev(fmaf(xi0, w0b.z, fmaf(xi1, w1b.z, fmaf(xi2, w2b.z, bbb.z)))) * m0b.z;
            y[7] = sinrev(fmaf(xi0, w0b.w, fmaf(xi1, w1b.w, fmaf(xi2, w2b.w, bbb.w)))) * m0b.w;

            bf16x8 bh, bl;
#pragma unroll
            for (int e = 0; e < 8; ++e) { short sh, sl; split_trunc(y[e], sh, sl); bh[e] = sh; bl[e] = sl; }

            bf16x8 ah0 = A1h[(t * 2 + 0) * 64 + l], al0 = A1l[(t * 2 + 0) * 64 + l];
            bf16x8 ah1 = A1h[(t * 2 + 1) * 64 + l], al1 = A1l[(t * 2 + 1) * 64 + l];
            acc0 = MFMA32(ah0, bh, acc0);
            acc1 = MFMA32(ah1, bh, acc1);
            acc0 = MFMA32(ah0, bl, acc0);
            acc1 = MFMA32(ah1, bl, acc1);
            acc0 = MFMA32(al0, bh, acc0);
            acc1 = MFMA32(al1, bh, acc1);
        }

        f32x16 ac20 = {}, ac21 = {};
#pragma unroll
        for (int t = 0; t < 4; ++t) {
            const f32x16& accA = (t < 2) ? acc0 : acc1;
            const int tb = t & 1;
            float4 bia_u = *(const float4*)&wbuf[L_SB1 + t * 16 + hh * 4];
            float4 bia_w = *(const float4*)&wbuf[L_SB1 + t * 16 + 8 + hh * 4];
            float4 mo_u  = *(const float4*)&mrow[64 + t * 16 + hh * 4];
            float4 mo_w  = *(const float4*)&mrow[64 + t * 16 + 8 + hh * 4];

            float fe[8];
#pragma unroll
            for (int j = 0; j < 4; ++j) {
                float uu = sinrev(accA[tb * 8 + j]     + C4(bia_u, j)) * C4(mo_u, j);
                float ww = sinrev(accA[tb * 8 + 4 + j] + C4(bia_w, j)) * C4(mo_w, j);
                float send = hh ? uu : ww;
                float recv = __shfl_xor(send, 32);
                fe[j]     = hh ? recv : uu;
                fe[4 + j] = hh ? ww : recv;
            }

            bf16x8 bh, bl;
#pragma unroll
            for (int e = 0; e < 8; ++e) { short sh, sl; split_trunc(fe[e], sh, sl); bh[e] = sh; bl[e] = sl; }

            bf16x8 ah0 = A2h[(t * 2 + 0) * 64 + l], al0 = A2l[(t * 2 + 0) * 64 + l];
            bf16x8 ah1 = A2h[(t * 2 + 1) * 64 + l], al1 = A2l[(t * 2 + 1) * 64 + l];
            ac20 = MFMA32(ah0, bh, ac20);
            ac21 = MFMA32(ah1, bh, ac21);
            ac20 = MFMA32(ah0, bl, ac20);
            ac21 = MFMA32(ah1, bl, ac21);
            ac20 = MFMA32(al0, bh, ac20);
            ac21 = MFMA32(al1, bh, ac21);
        }

        float dot = 0.f;
#pragma unroll
        for (int nt = 0; nt < 2; ++nt) {
#pragma unroll
            for (int g = 0; g < 4; ++g) {
                int n = nt * 32 + g * 8 + hh * 4;
                float4 bia = *(const float4*)&wbuf[L_SB2 + n];
                float4 mo  = *(const float4*)&mrow[128 + n];
                float4 lwv = *(const float4*)&wbuf[L_LW + n];
                float v0, v1, v2, v3;
                if (nt == 0) {
                    v0 = ac20[g * 4 + 0]; v1 = ac20[g * 4 + 1]; v2 = ac20[g * 4 + 2]; v3 = ac20[g * 4 + 3];
                } else {
                    v0 = ac21[g * 4 + 0]; v1 = ac21[g * 4 + 1]; v2 = ac21[g * 4 + 2]; v3 = ac21[g * 4 + 3];
                }
                dot = fmaf(sinrev(v0 + bia.x) * mo.x, lwv.x, dot);
                dot = fmaf(sinrev(v1 + bia.y) * mo.y, lwv.y, dot);
                dot = fmaf(sinrev(v2 + bia.z) * mo.z, lwv.z, dot);
                dot = fmaf(sinrev(v3 + bia.w) * mo.w, lwv.w, dot);
            }
        }
        dot += __shfl_xor(dot, 32);
        accO = fmaf(cw, dot + lb[0], accO);
    }

    if (hh == 0) out[P] = accO;
}

// ---------------------------------------------------------------------------
// Fallback: fully inline, one thread per point (only if ws too small).
// ---------------------------------------------------------------------------
__global__ void naive_decode(
        const float* __restrict__ x, const float* __restrict__ lv,
        const float* __restrict__ mw0, const float* __restrict__ mb0,
        const float* __restrict__ mw1, const float* __restrict__ mb1,
        const float* __restrict__ mw2, const float* __restrict__ mb2,
        const float* __restrict__ sw0, const float* __restrict__ sb0,
        const float* __restrict__ sw1, const float* __restrict__ sb1,
        const float* __restrict__ sw2, const float* __restrict__ sb2,
        const float* __restrict__ lw, const float* __restrict__ lb,
        float* __restrict__ out) {
    int P = blockIdx.x * blockDim.x + threadIdx.x;
    if (P >= NPTS) return;
    int b = P / NPER;
    float xs[3] = {x[P * 3 + 0], x[P * 3 + 1], x[P * 3 + 2]};
    float xg[3] = {xs[0] * 32.f, xs[1] * 32.f, xs[2] * 32.f};
    int lo[3], hi[3]; float lrp[3];
    for (int d = 0; d < 3; ++d) {
        int g0 = (int)(xg[d] - 0.5f), g1 = (int)(xg[d] + 0.5f);
        lo[d] = min(max(g0, 0), 31); hi[d] = min(max(g1, 0), 31);
        lrp[d] = xg[d] - 0.5f - (float)g0;
    }
    float acc = 0.f;
    for (int corner = 0; corner < 8; ++corner) {
        int ci = (corner >> 2) & 1, cj = (corner >> 1) & 1, ck = corner & 1;
        int c0 = ci ? hi[0] : lo[0], c1 = cj ? hi[1] : lo[1], c2 = ck ? hi[2] : lo[2];
        int idx = (c0 * 32 + c1) * 32 + c2;
        float cw = (ci ? lrp[0] : 1.f - lrp[0]) * (cj ? lrp[1] : 1.f - lrp[1]) * (ck ? lrp[2] : 1.f - lrp[2]);
        float xi0 = xg[0] - c0 - 0.5f, xi1 = xg[1] - c1 - 0.5f, xi2 = xg[2] - c2 - 0.5f;
        float lvv[32];
        for (int f = 0; f < 32; ++f) lvv[f] = lv[((size_t)(b * 32 + f) << 15) + idx];
        float m0[64], m1[64], m2[64];
        for (int j = 0; j < 64; ++j) { float s = mb0[j]; for (int i = 0; i < 32; ++i) s = fmaf(lvv[i], mw0[i * 64 + j], s); m0[j] = fmaxf(s, 0.f); }
        for (int j = 0; j < 64; ++j) { float s = mb1[j]; for (int i = 0; i < 64; ++i) s = fmaf(m0[i], mw1[i * 64 + j], s); for (int i = 0; i < 32; ++i) s = fmaf(lvv[i], mw1[(64 + i) * 64 + j], s); m1[j] = fmaxf(s, 0.f); }
        for (int j = 0; j < 64; ++j) { float s = mb2[j]; for (int i = 0; i < 64; ++i) s = fmaf(m1[i], mw2[i * 64 + j], s); for (int i = 0; i < 32; ++i) s = fmaf(lvv[i], mw2[(64 + i) * 64 + j], s); m2[j] = fmaxf(s, 0.f); }
        float s0[64];
        for (int j = 0; j < 64; ++j) s0[j] = __sinf(30.f * fmaf(xi0, sw0[j], fmaf(xi1, sw0[64 + j], fmaf(xi2, sw0[128 + j], sb0[j])))) * m0[j];
        float s1[64];
        for (int j = 0; j < 64; ++j) { float s = sb1[j]; for (int i = 0; i < 64; ++i) s = fmaf(s0[i], sw1[i * 64 + j], s); s1[j] = __sinf(s) * m1[j]; }
        float s2[64];
        for (int j = 0; j < 64; ++j) { float s = sb2[j]; for (int i = 0; i < 64; ++i) s = fmaf(s1[i], sw2[i * 64 + j], s); s2[j] = __sinf(s) * m2[j]; }
        float dot = lb[0];
        for (int i = 0; i < 64; ++i) dot = fmaf(s2[i], lw[i], dot);
        acc = fmaf(cw, dot, acc);
    }
    out[P] = acc;
}

extern "C" void kernel_launch(void* const* d_in, const int* in_sizes, int n_in,
                              void* d_out, int out_size, void* d_ws, size_t ws_size,
                              hipStream_t stream) {
    const float* x   = (const float*)d_in[0];
    const float* lv  = (const float*)d_in[1];
    const float* mw0 = (const float*)d_in[2];
    const float* mb0 = (const float*)d_in[3];
    const float* mw1 = (const float*)d_in[4];
    const float* mb1 = (const float*)d_in[5];
    const float* mw2 = (const float*)d_in[6];
    const float* mb2 = (const float*)d_in[7];
    const float* sw0 = (const float*)d_in[8];
    const float* sb0 = (const float*)d_in[9];
    const float* sw1 = (const float*)d_in[10];
    const float* sb1 = (const float*)d_in[11];
    const float* sw2 = (const float*)d_in[12];
    const float* sb2 = (const float*)d_in[13];
    const float* lw  = (const float*)d_in[14];
    const float* lb  = (const float*)d_in[15];
    float* out = (float*)d_out;
    float* ws  = (float*)d_ws;

    if (ws_size >= WS_NEEDED_BYTES) {
        int* counts = (int*)(ws + WS_COUNTS);
        float4* xs4 = (float4*)(ws + WS_XS4);
        prep_pack<<<64, 256, 0, stream>>>(sw1, sw2, mw0, mw1, mw2, ws, counts);
        sort_hist<<<(NPTS + 255) / 256, 256, 0, stream>>>(x, counts);
        sort_scan<<<1, 1024, 0, stream>>>(counts);
        sort_scatter<<<(NPTS + 255) / 256, 256, 0, stream>>>(x, counts, xs4);
        mods_mfma<<<NBINS / 128, 256, 0, stream>>>(lv, mb0, mb1, mb2, ws);
        decode_mfma<<<NBLK, 256, 0, stream>>>(
            ws, sw0, sb0, sb1, sb2, lw, lb, out);
    } else {
        naive_decode<<<(NPTS + 255) / 256, 256, 0, stream>>>(
            x, lv, mw0, mb0, mw1, mb1, mw2, mb2, sw0, sb0, sw1, sb1, sw2, sb2, lw, lb, out);
    }
}